// Round 5
// baseline (111.390 us; speedup 1.0000x reference)
//
#include <hip/hip_runtime.h>

#define NB   8
#define NDEP 64
#define KK   512
#define NP   12
#define NT   550
#define WIN  32                     // tick window per n, centered on floor(z)
#define ROWF 16                     // floats per compacted row (12 pm + ez + pad)
#define CH   16                     // ticks per K2 chunk
#define NCH  ((NT + CH - 1) / CH)   // 35
#define ROWS_FLOATS (NB * NDEP * KK * ROWF)   // 4,194,304 floats = 16 MB

// ---------------- K1: per-(b,n) MLP + survivor compaction into ws ----------------
__global__ __launch_bounds__(512) void k1_mlp(
    const float* __restrict__ ed,      // (8,64,4)
    const float* __restrict__ edraw,   // (8,64)
    const float* __restrict__ ddraw,   // (8,64,512,3)
    const float* __restrict__ udraw,   // (8,64,512)
    const float* __restrict__ W1, const float* __restrict__ b1,
    const float* __restrict__ W2, const float* __restrict__ b2,
    const float* __restrict__ dscale, const float* __restrict__ pscale,
    const float* __restrict__ life,
    float* __restrict__ ws)
{
    __shared__ float sW1[56], sb1[28], sW2[336], sb2[12], sS2[12], sD2[3];
    __shared__ int wcnt[8];

    const int tid = threadIdx.x;          // == k
    const int bn  = blockIdx.x;           // b*64+n

    if (tid < 336) sW2[tid] = W2[tid];
    if (tid < 56)  sW1[tid] = W1[tid];
    if (tid < 28)  sb1[tid] = b1[tid];
    if (tid < 12)  sb2[tid] = b2[tid];
    if (tid < 12)  { float s = pscale[tid]; sS2[tid] = s * s; }
    if (tid < 3)   { float s = dscale[tid]; sD2[tid] = s * s; }
    __syncthreads();

    const float4 dep  = ((const float4*)ed)[bn];
    const float nval  = dep.w * (1000000.0f / 22.4f);
    const float sigma = sqrtf(0.15f * nval);
    int ne = (int)(sigma * edraw[bn] + nval);        // trunc == astype(int32)
    ne = min(max(ne, 0), KK);
    const float sqz     = sqrtf(dep.z);
    const float invLife = 1.0f / life[0];

    const float* dd = ddraw + ((size_t)bn * KK + tid) * 3;
    const float d0 = dd[0], d1 = dd[1], d2 = dd[2];
    const float ez = fmaf(sD2[2] * d2, sqz, dep.z);
    const float prob = 1.0f - __expf(-ez * invLife);
    const bool live = (tid < ne) && (prob > udraw[(size_t)bn * KK + tid]);

    const unsigned long long bal = __ballot(live);
    const int lane = tid & 63;
    const int wv   = tid >> 6;                       // 0..7
    if (lane == 0) wcnt[wv] = __popcll(bal);
    __syncthreads();

    int base = 0, total = 0;
    #pragma unroll
    for (int w = 0; w < 8; ++w) {
        if (w < wv) base += wcnt[w];
        total += wcnt[w];
    }

    if (live) {
        const int slot = base + __popcll(bal & ((1ull << lane) - 1ull));
        const float ex = fmaf(sD2[0] * d0, sqz, dep.x);
        const float ey = fmaf(sD2[1] * d1, sqz, dep.y);

        float pm[NP];
        #pragma unroll
        for (int p = 0; p < NP; ++p) pm[p] = sb2[p];
        #pragma unroll 4
        for (int j = 0; j < 28; ++j) {
            float hj = fmaf(sW1[j], ex, fmaf(sW1[28 + j], ey, sb1[j]));
            hj = 1.0f / (1.0f + __expf(-hj));
            #pragma unroll
            for (int p = 0; p < NP; ++p) pm[p] = fmaf(hj, sW2[j * NP + p], pm[p]);
        }
        #pragma unroll
        for (int p = 0; p < NP; ++p) pm[p] = sS2[p] / (1.0f + __expf(-pm[p]));

        float4* row = (float4*)(ws + ((size_t)bn * KK + slot) * ROWF);
        row[0] = make_float4(pm[0], pm[1],  pm[2],  pm[3]);
        row[1] = make_float4(pm[4], pm[5],  pm[6],  pm[7]);
        row[2] = make_float4(pm[8], pm[9],  pm[10], pm[11]);
        row[3] = make_float4(ez, 0.0f, 0.0f, 0.0f);
    }

    if (tid == 0) {
        int2* hdr = (int2*)(ws + ROWS_FLOATS);
        hdr[bn] = make_int2((int)floorf(dep.z) - WIN / 2, total);
    }
}

// ---------------- K2: output-stationary gather; every out element written once ----------------
__global__ __launch_bounds__(256) void k2_gather(
    const float* __restrict__ ws,
    float* __restrict__ out)
{
    __shared__ int hT[NDEP], hL[NDEP];
    __shared__ float part[16 * 16 * NP];   // [sub][tw][p], 12 KB

    const int tid = threadIdx.x;
    const int b   = blockIdx.x / NCH;
    const int ch  = blockIdx.x % NCH;
    const int c0  = ch * CH;

    if (tid < NDEP) {
        const int2 h = ((const int2*)(ws + ROWS_FLOATS))[b * NDEP + tid];
        hT[tid] = h.x; hL[tid] = h.y;
    }
    __syncthreads();

    const int   tw  = tid & 15;
    const int   sub = tid >> 4;            // 0..15
    const float tc  = (float)(c0 + tw) + 0.5f;

    float a0x=0,a0y=0,a0z=0,a0w=0, a1x=0,a1y=0,a1z=0,a1w=0, a2x=0,a2y=0,a2z=0,a2w=0;

    for (int n = 0; n < NDEP; ++n) {
        const int tb = hT[n], lv = hL[n];
        if (tb < c0 + CH && tb + WIN > c0 && lv > 0) {      // block-uniform branch
            const float* rbase = ws + ((size_t)(b * NDEP + n) * KK) * ROWF;
            for (int k = sub; k < lv; k += 16) {
                const float4* r = (const float4*)(rbase + k * ROWF);
                const float4 r0 = r[0], r1 = r[1], r2 = r[2], r3 = r[3];
                const float d = tc - r3.x;
                const float g = 3.9894228040143274f * __expf(-10.0f * d * d);
                a0x = fmaf(r0.x, g, a0x); a0y = fmaf(r0.y, g, a0y);
                a0z = fmaf(r0.z, g, a0z); a0w = fmaf(r0.w, g, a0w);
                a1x = fmaf(r1.x, g, a1x); a1y = fmaf(r1.y, g, a1y);
                a1z = fmaf(r1.z, g, a1z); a1w = fmaf(r1.w, g, a1w);
                a2x = fmaf(r2.x, g, a2x); a2y = fmaf(r2.y, g, a2y);
                a2z = fmaf(r2.z, g, a2z); a2w = fmaf(r2.w, g, a2w);
            }
        }
    }

    {
        float* pp = &part[(sub * 16 + tw) * NP];
        pp[0]=a0x; pp[1]=a0y; pp[2]=a0z; pp[3]=a0w;
        pp[4]=a1x; pp[5]=a1y; pp[6]=a1z; pp[7]=a1w;
        pp[8]=a2x; pp[9]=a2y; pp[10]=a2z; pp[11]=a2w;
    }
    __syncthreads();

    if (tid < 16 * NP) {                   // 192 threads: (tw, p)
        const int twi = tid / NP;
        const int p   = tid - twi * NP;
        float s = 0.0f;
        #pragma unroll
        for (int c = 0; c < 16; ++c) s += part[(c * 16 + twi) * NP + p];
        const int t = c0 + twi;
        if (t < NT) out[((size_t)b * NP + p) * NT + t] = s;
    }
}

extern "C" void kernel_launch(void* const* d_in, const int* in_sizes, int n_in,
                              void* d_out, int out_size, void* d_ws, size_t ws_size,
                              hipStream_t stream) {
    const float* ed     = (const float*)d_in[0];
    const float* edraw  = (const float*)d_in[1];
    const float* ddraw  = (const float*)d_in[2];
    const float* udraw  = (const float*)d_in[3];
    const float* W1     = (const float*)d_in[4];
    const float* b1     = (const float*)d_in[5];
    const float* W2     = (const float*)d_in[6];
    const float* b2     = (const float*)d_in[7];
    const float* dscale = (const float*)d_in[8];
    const float* pscale = (const float*)d_in[9];
    const float* life   = (const float*)d_in[10];
    float* ws  = (float*)d_ws;
    float* out = (float*)d_out;

    k1_mlp<<<NB * NDEP, 512, 0, stream>>>(ed, edraw, ddraw, udraw,
                                          W1, b1, W2, b2, dscale, pscale, life, ws);
    k2_gather<<<NB * NCH, 256, 0, stream>>>(ws, out);
}

// Round 6
// 96.353 us; speedup vs baseline: 1.1561x; 1.1561x over previous
//
#include <hip/hip_runtime.h>

#define NB   8
#define NDEP 64
#define KK   512
#define NP   12
#define NT   550
#define WIN  32                     // tick window per n, centered on floor(z)
#define CH   16                     // ticks owned per block
#define NCH  ((NT + CH - 1) / CH)   // 35 chunks
#define ROWF 16                     // floats per compacted LDS row: pm[12], ez, pad

__global__ __launch_bounds__(512) void next_sim_fused(
    const float* __restrict__ ed,      // (8,64,4) x,y,z,E
    const float* __restrict__ edraw,   // (8,64)
    const float* __restrict__ ddraw,   // (8,64,512,3)
    const float* __restrict__ udraw,   // (8,64,512)
    const float* __restrict__ W1, const float* __restrict__ b1,
    const float* __restrict__ W2, const float* __restrict__ b2,
    const float* __restrict__ dscale, const float* __restrict__ pscale,
    const float* __restrict__ life,
    float* __restrict__ out)           // (8,12,550)
{
    __shared__ __align__(16) float rows[KK * ROWF];   // 32 KB; reused for reduction
    __shared__ float sW1[56], sb1[28], sW2[336], sb2[12], sS2[12], sD2[3];
    __shared__ int nlist[NDEP];
    __shared__ int ncount;
    __shared__ int wcnt[8];

    const int tid = threadIdx.x;
    const int b   = blockIdx.x / NCH;
    const int ch  = blockIdx.x % NCH;
    const int c0  = ch * CH;

    if (tid < 336) sW2[tid] = W2[tid];
    if (tid < 56)  sW1[tid] = W1[tid];
    if (tid < 28)  sb1[tid] = b1[tid];
    if (tid < 12)  sb2[tid] = b2[tid];
    if (tid < 12)  { float s = pscale[tid]; sS2[tid] = s * s; }
    if (tid < 3)   { float s = dscale[tid]; sD2[tid] = s * s; }

    const float invLife = 1.0f / life[0];

    // ---- header pass (wave 0): which n's windows overlap this chunk?
    if (tid < NDEP) {
        const float4 dep = ((const float4*)ed)[b * NDEP + tid];
        const float nval  = dep.w * (1000000.0f / 22.4f);
        const float sigma = sqrtf(0.15f * nval);
        int ne = (int)(sigma * edraw[b * NDEP + tid] + nval);
        ne = min(max(ne, 0), KK);
        const int tb = (int)floorf(dep.z) - WIN / 2;
        const bool ov = (ne > 0) && (tb < c0 + CH) && (tb + WIN > c0);
        const unsigned long long bal = __ballot(ov);
        if (ov) nlist[__popcll(bal & ((1ull << tid) - 1ull))] = tid;
        if (tid == 0) ncount = __popcll(bal);
    }
    __syncthreads();

    const int nc  = ncount;
    const int tw  = tid & (CH - 1);
    const int sub = tid >> 4;                      // 0..31
    const float tc = (float)(c0 + tw) + 0.5f;
    float a0x=0,a0y=0,a0z=0,a0w=0, a1x=0,a1y=0,a1z=0,a1w=0, a2x=0,a2y=0,a2z=0,a2w=0;

    for (int ni = 0; ni < nc; ++ni) {
        const int n  = nlist[ni];
        const int bn = b * NDEP + n;

        const float4 dep  = ((const float4*)ed)[bn];
        const float nval  = dep.w * (1000000.0f / 22.4f);
        const float sigma = sqrtf(0.15f * nval);
        int ne = (int)(sigma * edraw[bn] + nval);  // trunc toward 0 == astype(int32)
        ne = min(max(ne, 0), KK);
        const float sqz = sqrtf(dep.z);

        // ---- phase A: k = tid; survival + ballot-compacted MLP rows into LDS
        const float* dd = ddraw + ((size_t)bn * KK + tid) * 3;
        const float d0 = dd[0], d1 = dd[1], d2 = dd[2];
        const float ez = fmaf(sD2[2] * d2, sqz, dep.z);
        const float prob = 1.0f - __expf(-ez * invLife);
        const bool live = (tid < ne) && (prob > udraw[(size_t)bn * KK + tid]);

        const unsigned long long bal = __ballot(live);
        const int lane = tid & 63;
        const int wv   = tid >> 6;
        if (lane == 0) wcnt[wv] = __popcll(bal);
        __syncthreads();

        int base = 0, total = 0;
        #pragma unroll
        for (int w = 0; w < 8; ++w) {
            const int c = wcnt[w];
            if (w < wv) base += c;
            total += c;
        }

        if (live) {
            const int slot = base + __popcll(bal & ((1ull << lane) - 1ull));
            const float ex = fmaf(sD2[0] * d0, sqz, dep.x);
            const float ey = fmaf(sD2[1] * d1, sqz, dep.y);
            float pm[NP];
            #pragma unroll
            for (int p = 0; p < NP; ++p) pm[p] = sb2[p];
            #pragma unroll 4
            for (int j = 0; j < 28; ++j) {
                float hj = fmaf(sW1[j], ex, fmaf(sW1[28 + j], ey, sb1[j]));
                hj = 1.0f / (1.0f + __expf(-hj));
                #pragma unroll
                for (int p = 0; p < NP; ++p) pm[p] = fmaf(hj, sW2[j * NP + p], pm[p]);
            }
            float4* row = (float4*)&rows[slot * ROWF];
            row[0] = make_float4(sS2[0] / (1.0f + __expf(-pm[0])),
                                 sS2[1] / (1.0f + __expf(-pm[1])),
                                 sS2[2] / (1.0f + __expf(-pm[2])),
                                 sS2[3] / (1.0f + __expf(-pm[3])));
            row[1] = make_float4(sS2[4] / (1.0f + __expf(-pm[4])),
                                 sS2[5] / (1.0f + __expf(-pm[5])),
                                 sS2[6] / (1.0f + __expf(-pm[6])),
                                 sS2[7] / (1.0f + __expf(-pm[7])));
            row[2] = make_float4(sS2[8]  / (1.0f + __expf(-pm[8])),
                                 sS2[9]  / (1.0f + __expf(-pm[9])),
                                 sS2[10] / (1.0f + __expf(-pm[10])),
                                 sS2[11] / (1.0f + __expf(-pm[11])));
            rows[slot * ROWF + 12] = ez;
        }
        __syncthreads();

        // ---- phase B: gather rows into per-thread (tw) accumulators
        for (int k = sub; k < total; k += 32) {
            const float4* r = (const float4*)&rows[k * ROWF];
            const float4 r0 = r[0], r1 = r[1], r2 = r[2];
            const float ezr = rows[k * ROWF + 12];
            const float d  = tc - ezr;
            const float g  = 3.9894228040143274f * __expf(-10.0f * d * d);
            a0x = fmaf(r0.x, g, a0x); a0y = fmaf(r0.y, g, a0y);
            a0z = fmaf(r0.z, g, a0z); a0w = fmaf(r0.w, g, a0w);
            a1x = fmaf(r1.x, g, a1x); a1y = fmaf(r1.y, g, a1y);
            a1z = fmaf(r1.z, g, a1z); a1w = fmaf(r1.w, g, a1w);
            a2x = fmaf(r2.x, g, a2x); a2y = fmaf(r2.y, g, a2y);
            a2z = fmaf(r2.z, g, a2z); a2w = fmaf(r2.w, g, a2w);
        }
        __syncthreads();   // rows[] consumed before next n overwrites
    }

    // ---- reduction: park 512×12 partials (stride 16), sum over sub, exact-once store
    {
        float4* prow = (float4*)&rows[tid * ROWF];
        prow[0] = make_float4(a0x, a0y, a0z, a0w);
        prow[1] = make_float4(a1x, a1y, a1z, a1w);
        prow[2] = make_float4(a2x, a2y, a2z, a2w);
    }
    __syncthreads();

    if (tid < CH * NP) {                 // 192 threads: (twi, p)
        const int twi = tid / NP;
        const int p   = tid - twi * NP;
        float s = 0.0f;
        #pragma unroll
        for (int c = 0; c < 32; ++c) s += rows[(c * CH + twi) * ROWF + p];
        const int t = c0 + twi;
        if (t < NT) out[((size_t)b * NP + p) * NT + t] = s;
    }
}

extern "C" void kernel_launch(void* const* d_in, const int* in_sizes, int n_in,
                              void* d_out, int out_size, void* d_ws, size_t ws_size,
                              hipStream_t stream) {
    const float* ed     = (const float*)d_in[0];
    const float* edraw  = (const float*)d_in[1];
    const float* ddraw  = (const float*)d_in[2];
    const float* udraw  = (const float*)d_in[3];
    const float* W1     = (const float*)d_in[4];
    const float* b1     = (const float*)d_in[5];
    const float* W2     = (const float*)d_in[6];
    const float* b2     = (const float*)d_in[7];
    const float* dscale = (const float*)d_in[8];
    const float* pscale = (const float*)d_in[9];
    const float* life   = (const float*)d_in[10];
    float* out = (float*)d_out;

    next_sim_fused<<<NB * NCH, 512, 0, stream>>>(
        ed, edraw, ddraw, udraw, W1, b1, W2, b2, dscale, pscale, life, out);
}

// Round 7
// 22.970 us; speedup vs baseline: 4.8494x; 4.1947x over previous
//
#include <hip/hip_runtime.h>
#include <hip/hip_fp16.h>

#define NB   8
#define NDEP 64
#define KK   512
#define NP   12
#define NT   550

static __device__ __forceinline__ float sigmoidf_fast(float x) {
    return 1.0f / (1.0f + __expf(-x));
}
static __device__ __forceinline__ unsigned packh2(float a, float b) {
    __half2 h = __floats2half2_rn(a, b);
    return __builtin_bit_cast(unsigned, h);
}
static __device__ __forceinline__ float2 unpackh2(unsigned u) {
    return __half22float2(__builtin_bit_cast(__half2, u));
}

// LDS row layout: row k at dword offset k*8 + (k>>4)*4  (16B pad per 16 rows).
// Gather (S subs, W=64/S stations): iter i, sub s reads row s*W+i -> the pad
// spreads the S concurrent 16B reads across distinct bank groups.
template<int S>
static __device__ __forceinline__ void gather_reduce(
    const unsigned* __restrict__ wl, int lane, int t_lo, int b,
    float* __restrict__ out)
{
    constexpr int W = 64 / S;
    const int tw  = lane & (W - 1);
    const int sub = lane / W;
    const float tc = (float)(t_lo + tw) + 0.5f;

    float acc[NP];
    #pragma unroll
    for (int p = 0; p < NP; ++p) acc[p] = 0.0f;

    #pragma unroll 4
    for (int i = 0; i < W; ++i) {
        const int k = sub * W + i;
        const int o = k * 8 + ((k >> 4) << 2);
        const uint4 r0 = *(const uint4*)&wl[o];
        const uint4 r1 = *(const uint4*)&wl[o + 4];
        const float ez = __builtin_bit_cast(float, r1.z);
        const float d  = tc - ez;
        const float g  = exp2f(-14.426950408889634f * d * d);  // exp(-10 d^2)
        const float2 u0 = unpackh2(r0.x), u1 = unpackh2(r0.y);
        const float2 u2 = unpackh2(r0.z), u3 = unpackh2(r0.w);
        const float2 u4 = unpackh2(r1.x), u5 = unpackh2(r1.y);
        acc[0] = fmaf(u0.x, g, acc[0]);  acc[1]  = fmaf(u0.y, g, acc[1]);
        acc[2] = fmaf(u1.x, g, acc[2]);  acc[3]  = fmaf(u1.y, g, acc[3]);
        acc[4] = fmaf(u2.x, g, acc[4]);  acc[5]  = fmaf(u2.y, g, acc[5]);
        acc[6] = fmaf(u3.x, g, acc[6]);  acc[7]  = fmaf(u3.y, g, acc[7]);
        acc[8] = fmaf(u4.x, g, acc[8]);  acc[9]  = fmaf(u4.y, g, acc[9]);
        acc[10] = fmaf(u5.x, g, acc[10]); acc[11] = fmaf(u5.y, g, acc[11]);
    }

    // combine the S sub-partials per station
    #pragma unroll
    for (int msk = W; msk < 64; msk <<= 1) {
        #pragma unroll
        for (int p = 0; p < NP; ++p) acc[p] += __shfl_xor(acc[p], msk);
    }

    if (lane < W) {
        float* ob = out + ((size_t)b * NP) * NT + (t_lo + tw);
        #pragma unroll
        for (int p = 0; p < NP; ++p) atomicAdd(&ob[p * NT], acc[p]);
    }
}

__global__ __launch_bounds__(256) void next_sim_wave(
    const float* __restrict__ ed,      // (8,64,4) x,y,z,E
    const float* __restrict__ edraw,   // (8,64)
    const float* __restrict__ ddraw,   // (8,64,512,3)
    const float* __restrict__ udraw,   // (8,64,512)
    const float* __restrict__ W1, const float* __restrict__ b1,
    const float* __restrict__ W2, const float* __restrict__ b2,
    const float* __restrict__ dscale, const float* __restrict__ pscale,
    const float* __restrict__ life,
    float* __restrict__ out)           // (8,12,550)
{
    __shared__ unsigned lds[4][544];   // per-wave private 2176 B region

    const int tid  = threadIdx.x;
    const int lane = tid & 63;
    const int wid  = tid >> 6;
    const int bid  = blockIdx.x;       // 1024 blocks: bn*2 + half
    const int bn   = bid >> 1;
    const int g    = ((bid & 1) << 2) | wid;   // k-group 0..7
    const int b    = bn >> 6;

    // wave-uniform header (scalarizable loads)
    const float4 dep  = ((const float4*)ed)[bn];
    const float nval  = dep.w * (1000000.0f / 22.4f);
    const float sigma = sqrtf(0.15f * nval);
    int ne = (int)(sigma * edraw[bn] + nval);     // trunc == astype(int32)
    ne = min(max(ne, 0), KK);
    const int k0 = g << 6;
    if (k0 >= ne) return;                          // dead wave: early exit

    const float sqz     = sqrtf(dep.z);
    const float invLife = 1.0f / life[0];
    const float dS0 = dscale[0] * dscale[0];
    const float dS1 = dscale[1] * dscale[1];
    const float dS2 = dscale[2] * dscale[2];

    // per-lane electron
    const int k = k0 + lane;
    const float* dd = ddraw + ((size_t)bn * KK + k) * 3;
    const float d0 = dd[0], d1 = dd[1], d2 = dd[2];
    const float ez = fmaf(dS2 * d2, sqz, dep.z);
    const float ex = fmaf(dS0 * d0, sqz, dep.x);
    const float ey = fmaf(dS1 * d1, sqz, dep.y);
    const float prob = 1.0f - __expf(-ez * invLife);
    const float m = ((k < ne) && (prob > udraw[(size_t)bn * KK + k])) ? 1.0f : 0.0f;

    // MLP; weights read with uniform indices from global -> SGPR (s_load)
    float pm[NP];
    #pragma unroll
    for (int p = 0; p < NP; ++p) pm[p] = b2[p];
    #pragma unroll 4
    for (int j = 0; j < 28; ++j) {
        const float hj = sigmoidf_fast(fmaf(W1[j], ex, fmaf(W1[28 + j], ey, b1[j])));
        #pragma unroll
        for (int p = 0; p < NP; ++p) pm[p] = fmaf(hj, W2[j * NP + p], pm[p]);
    }
    const float gm = 3.9894228040143274f * m;      // fold GAUSS_NORM + mask
    float q[NP];
    #pragma unroll
    for (int p = 0; p < NP; ++p)
        q[p] = pscale[p] * pscale[p] * gm * sigmoidf_fast(pm[p]);

    // write this lane's 32-B row into the wave-private LDS region
    unsigned* wl = lds[wid];
    const int off = lane * 8 + ((lane >> 4) << 2);
    uint4 r0, r1;
    r0.x = packh2(q[0], q[1]);   r0.y = packh2(q[2],  q[3]);
    r0.z = packh2(q[4], q[5]);   r0.w = packh2(q[6],  q[7]);
    r1.x = packh2(q[8], q[9]);   r1.y = packh2(q[10], q[11]);
    r1.z = __builtin_bit_cast(unsigned, ez);  r1.w = 0u;
    *(uint4*)&wl[off]     = r0;
    *(uint4*)&wl[off + 4] = r1;

    // wave ez min/max -> adaptive window
    float ezmin = ez, ezmax = ez;
    #pragma unroll
    for (int msk = 1; msk < 64; msk <<= 1) {
        ezmin = fminf(ezmin, __shfl_xor(ezmin, msk));
        ezmax = fmaxf(ezmax, __shfl_xor(ezmax, msk));
    }
    const int fmin = (int)floorf(ezmin);
    const int fmax = (int)floorf(ezmax);
    const int need = fmax - fmin + 7;   // +-3 ticks around [fmin, fmax]

    if (need <= 16) {
        const int t_lo = min(max(fmin - 3, 0), NT - 16);
        gather_reduce<4>(wl, lane, t_lo, b, out);
    } else {
        const int t_lo = min(max(fmin - 3, 0), NT - 32);
        gather_reduce<2>(wl, lane, t_lo, b, out);
    }
}

extern "C" void kernel_launch(void* const* d_in, const int* in_sizes, int n_in,
                              void* d_out, int out_size, void* d_ws, size_t ws_size,
                              hipStream_t stream) {
    const float* ed     = (const float*)d_in[0];
    const float* edraw  = (const float*)d_in[1];
    const float* ddraw  = (const float*)d_in[2];
    const float* udraw  = (const float*)d_in[3];
    const float* W1     = (const float*)d_in[4];
    const float* b1     = (const float*)d_in[5];
    const float* W2     = (const float*)d_in[6];
    const float* b2     = (const float*)d_in[7];
    const float* dscale = (const float*)d_in[8];
    const float* pscale = (const float*)d_in[9];
    const float* life   = (const float*)d_in[10];
    float* out = (float*)d_out;

    hipMemsetAsync(d_out, 0, (size_t)out_size * sizeof(float), stream);
    next_sim_wave<<<NB * NDEP * 2, 256, 0, stream>>>(
        ed, edraw, ddraw, udraw, W1, b1, W2, b2, dscale, pscale, life, out);
}

// Round 8
// 20.658 us; speedup vs baseline: 5.3920x; 1.1119x over previous
//
#include <hip/hip_runtime.h>
#include <hip/hip_fp16.h>

#define NB   8
#define NDEP 64
#define KK   512
#define NP   12
#define NT   550
#define L2E  1.4426950408889634f

// ws table layout (dwords):
//  [0..27]    w1a  = W1[0][j]*L2E
//  [28..55]   w1b  = W1[1][j]*L2E
//  [56..83]   b1s  = b1[j]*L2E
//  [84..251]  w2pk = half2(W2[j][2c], W2[j][2c+1])   (j*6+c)
//  [252..257] b2pk = half2(b2[2c], b2[2c+1])
//  [258..269] qtab = pscale[p]^2 * GAUSS_NORM

static __device__ __forceinline__ float fast_rcp(float x) {
    return __builtin_amdgcn_rcpf(x);
}
static __device__ __forceinline__ unsigned packh2(float a, float b) {
    __half2 h = __floats2half2_rn(a, b);
    return __builtin_bit_cast(unsigned, h);
}

__global__ __launch_bounds__(256) void init_kernel(
    const float* __restrict__ W1, const float* __restrict__ b1,
    const float* __restrict__ W2, const float* __restrict__ b2,
    const float* __restrict__ pscale,
    float* __restrict__ ws, float* __restrict__ out, int out_size)
{
    const int idx = blockIdx.x * 256 + threadIdx.x;
    for (int i = idx; i < out_size; i += gridDim.x * 256) out[i] = 0.0f;

    if (blockIdx.x == 0) {
        const int t = threadIdx.x;
        if (t < 28) {
            ws[t]      = W1[t]      * L2E;
            ws[28 + t] = W1[28 + t] * L2E;
            ws[56 + t] = b1[t]      * L2E;
        }
        if (t >= 64 && t < 232) {              // 168 packed W2 entries
            const int e = t - 64, j = e / 6, c = e - j * 6;
            ((unsigned*)(ws + 84))[e] = packh2(W2[j * NP + 2 * c], W2[j * NP + 2 * c + 1]);
        }
        if (t >= 232 && t < 238) {
            const int c = t - 232;
            ((unsigned*)(ws + 252))[c] = packh2(b2[2 * c], b2[2 * c + 1]);
        }
        if (t >= 238 && t < 250) {
            const int p = t - 238;
            ws[258 + p] = pscale[p] * pscale[p] * 3.9894228040143274f;
        }
    }
}

// LDS row k at dword offset k*16 + (k>>4)*4 (16B pad per 16 rows): the S
// concurrent sub reads land on distinct bank groups.
template<int S>
static __device__ __forceinline__ void gather_reduce(
    const float* __restrict__ wl, int lane, int t_lo, int b,
    float* __restrict__ out)
{
    constexpr int W = 64 / S;
    const int tw  = lane & (W - 1);
    const int sub = lane / W;
    const float tc = (float)(t_lo + tw) + 0.5f;

    float acc[NP];
    #pragma unroll
    for (int p = 0; p < NP; ++p) acc[p] = 0.0f;

    #pragma unroll 4
    for (int i = 0; i < W; ++i) {
        const int k = sub * W + i;
        const int o = (k << 4) + ((k >> 4) << 2);
        const float4 r0 = *(const float4*)&wl[o];
        const float4 r1 = *(const float4*)&wl[o + 4];
        const float4 r2 = *(const float4*)&wl[o + 8];
        const float ez  = wl[o + 12];
        const float d   = tc - ez;
        const float g   = exp2f(-14.426950408889634f * d * d);   // exp(-10 d^2)
        acc[0]  = fmaf(r0.x, g, acc[0]);  acc[1]  = fmaf(r0.y, g, acc[1]);
        acc[2]  = fmaf(r0.z, g, acc[2]);  acc[3]  = fmaf(r0.w, g, acc[3]);
        acc[4]  = fmaf(r1.x, g, acc[4]);  acc[5]  = fmaf(r1.y, g, acc[5]);
        acc[6]  = fmaf(r1.z, g, acc[6]);  acc[7]  = fmaf(r1.w, g, acc[7]);
        acc[8]  = fmaf(r2.x, g, acc[8]);  acc[9]  = fmaf(r2.y, g, acc[9]);
        acc[10] = fmaf(r2.z, g, acc[10]); acc[11] = fmaf(r2.w, g, acc[11]);
    }

    #pragma unroll
    for (int msk = W; msk < 64; msk <<= 1) {
        #pragma unroll
        for (int p = 0; p < NP; ++p) acc[p] += __shfl_xor(acc[p], msk);
    }

    if (lane < W) {
        float* ob = out + ((size_t)b * NP) * NT + (t_lo + tw);
        #pragma unroll
        for (int p = 0; p < NP; ++p) atomicAdd(&ob[p * NT], acc[p]);
    }
}

__global__ __launch_bounds__(256) void next_sim_wave(
    const float* __restrict__ ed,      // (8,64,4) x,y,z,E
    const float* __restrict__ edraw,   // (8,64)
    const float* __restrict__ ddraw,   // (8,64,512,3)
    const float* __restrict__ udraw,   // (8,64,512)
    const float* __restrict__ wst,     // packed weight table (ws)
    const float* __restrict__ dscale, const float* __restrict__ life,
    float* __restrict__ out)           // (8,12,550)
{
    __shared__ float lds[4][1040];     // per-wave private f32 rows (16+pad stride)

    const int tid  = threadIdx.x;
    const int lane = tid & 63;
    const int wid  = tid >> 6;
    const int bid  = blockIdx.x;       // 1024 blocks: bn*2 + half
    const int bn   = bid >> 1;
    const int g    = ((bid & 1) << 2) | wid;   // k-group 0..7
    const int b    = bn >> 6;

    // wave-uniform header
    const float4 dep  = ((const float4*)ed)[bn];
    const float nval  = dep.w * (1000000.0f / 22.4f);
    const float sigma = sqrtf(0.15f * nval);
    int ne = (int)(sigma * edraw[bn] + nval);     // trunc == astype(int32)
    ne = min(max(ne, 0), KK);
    const int k0 = g << 6;
    if (k0 >= ne) return;                          // dead wave: early exit

    const float sqz     = sqrtf(dep.z);
    const float invLife = fast_rcp(life[0]);
    const float dS0 = dscale[0] * dscale[0];
    const float dS1 = dscale[1] * dscale[1];
    const float dS2 = dscale[2] * dscale[2];

    // per-lane electron
    const int k = k0 + lane;
    const float* dd = ddraw + ((size_t)bn * KK + k) * 3;
    const float d0 = dd[0], d1 = dd[1], d2 = dd[2];
    const float ez = fmaf(dS2 * d2, sqz, dep.z);
    const float ex = fmaf(dS0 * d0, sqz, dep.x);
    const float ey = fmaf(dS1 * d1, sqz, dep.y);
    const float prob = 1.0f - __expf(-ez * invLife);
    const float m = ((k < ne) && (prob > udraw[(size_t)bn * KK + k])) ? 1.0f : 0.0f;

    // MLP: hidden f32 (pre-scaled weights -> exp2), output layer packed f16
    const float*   w1a  = wst;
    const float*   w1b  = wst + 28;
    const float*   b1s  = wst + 56;
    const __half2* w2pk = (const __half2*)(wst + 84);
    const __half2* b2pk = (const __half2*)(wst + 252);
    const float*   qtab = wst + 258;

    __half2 pa0 = b2pk[0], pa1 = b2pk[1], pa2 = b2pk[2];
    __half2 pa3 = b2pk[3], pa4 = b2pk[4], pa5 = b2pk[5];
    #pragma unroll 4
    for (int j = 0; j < 28; ++j) {
        const float lg  = fmaf(w1a[j], ex, fmaf(w1b[j], ey, b1s[j]));
        const float hjf = fast_rcp(1.0f + exp2f(-lg));
        const __half2 h2 = __float2half2_rn(hjf);
        pa0 = __hfma2(h2, w2pk[j * 6 + 0], pa0);
        pa1 = __hfma2(h2, w2pk[j * 6 + 1], pa1);
        pa2 = __hfma2(h2, w2pk[j * 6 + 2], pa2);
        pa3 = __hfma2(h2, w2pk[j * 6 + 3], pa3);
        pa4 = __hfma2(h2, w2pk[j * 6 + 4], pa4);
        pa5 = __hfma2(h2, w2pk[j * 6 + 5], pa5);
    }
    float pm[NP];
    { float2 f;
      f = __half22float2(pa0); pm[0] = f.x; pm[1] = f.y;
      f = __half22float2(pa1); pm[2] = f.x; pm[3] = f.y;
      f = __half22float2(pa2); pm[4] = f.x; pm[5] = f.y;
      f = __half22float2(pa3); pm[6] = f.x; pm[7] = f.y;
      f = __half22float2(pa4); pm[8] = f.x; pm[9] = f.y;
      f = __half22float2(pa5); pm[10] = f.x; pm[11] = f.y; }

    float q[NP];
    #pragma unroll
    for (int p = 0; p < NP; ++p)
        q[p] = qtab[p] * m * fast_rcp(1.0f + exp2f(-pm[p] * L2E));

    // write this lane's f32 row into the wave-private LDS region
    float* wl = lds[wid];
    const int off = (lane << 4) + ((lane >> 4) << 2);
    *(float4*)&wl[off]     = make_float4(q[0], q[1],  q[2],  q[3]);
    *(float4*)&wl[off + 4] = make_float4(q[4], q[5],  q[6],  q[7]);
    *(float4*)&wl[off + 8] = make_float4(q[8], q[9],  q[10], q[11]);
    wl[off + 12] = ez;

    // wave ez min/max -> adaptive window
    float ezmin = ez, ezmax = ez;
    #pragma unroll
    for (int msk = 1; msk < 64; msk <<= 1) {
        ezmin = fminf(ezmin, __shfl_xor(ezmin, msk));
        ezmax = fmaxf(ezmax, __shfl_xor(ezmax, msk));
    }
    const int fmin = (int)floorf(ezmin);
    const int fmax = (int)floorf(ezmax);
    const int need = fmax - fmin + 7;   // +-3 ticks around [fmin, fmax]

    if (need <= 16) {
        const int t_lo = min(max(fmin - 3, 0), NT - 16);
        gather_reduce<4>(wl, lane, t_lo, b, out);
    } else {
        const int t_lo = min(max(fmin - 3, 0), NT - 32);
        gather_reduce<2>(wl, lane, t_lo, b, out);
    }
}

extern "C" void kernel_launch(void* const* d_in, const int* in_sizes, int n_in,
                              void* d_out, int out_size, void* d_ws, size_t ws_size,
                              hipStream_t stream) {
    const float* ed     = (const float*)d_in[0];
    const float* edraw  = (const float*)d_in[1];
    const float* ddraw  = (const float*)d_in[2];
    const float* udraw  = (const float*)d_in[3];
    const float* W1     = (const float*)d_in[4];
    const float* b1     = (const float*)d_in[5];
    const float* W2     = (const float*)d_in[6];
    const float* b2     = (const float*)d_in[7];
    const float* dscale = (const float*)d_in[8];
    const float* pscale = (const float*)d_in[9];
    const float* life   = (const float*)d_in[10];
    float* ws  = (float*)d_ws;
    float* out = (float*)d_out;

    init_kernel<<<64, 256, 0, stream>>>(W1, b1, W2, b2, pscale, ws, out, out_size);
    next_sim_wave<<<NB * NDEP * 2, 256, 0, stream>>>(
        ed, edraw, ddraw, udraw, ws, dscale, life, out);
}